// Round 2
// baseline (244.352 us; speedup 1.0000x reference)
//
#include <hip/hip_runtime.h>

// FastVolterra1: out[r,:] = irfft(rfft(x[r,:]) * softmax(w1)), D=1024, fp32.
//
// Real-packed: z[n] = x[2n] + i*x[2n+1] (length 512);
//   Z = FFT_512(z);  W[k] = P[k]*Z[k] + i*q[k]*conj(Z[(512-k)%512]);
//   w = IFFT_512(W); out[2n]=Re w[n], out[2n+1]=Im w[n].
// P,q real, precomputed from softmax gate (1/512 norm folded in).
//
// FFT-512 = 3 radix-8 Stockham stages. 64 threads/row; one row's LDS traffic
// stays within one wave -> NO __syncthreads (same-wave LDS ops are in-order).
//
// R2 (this round): latency-bound fix. rocprof showed ALL pipes <35% busy at
// 81us (VALU 26, HBM 31, LDS ~30) => dependent-chain latency dominates, not
// throughput. Changes:
//  (a) TWO ROWS PER WAVE, phase-interleaved: row B's butterflies issue while
//      row A waits on LDS/shuffle latency (in-wave ILP instead of relying on
//      wave overlap that measurably wasn't happening). 8 rows/block,
//      LDS 36,352 B/block -> 4 blocks/CU, 32 resident rows/CU (unchanged),
//      but 2 independent chains per wave + global-load latency amortized 2x.
//  (b) Bank conflicts (4.19M last round = 8 cyc x 16 stage-2 stores/wave,
//      confirmed by 16-lane-quarter math): the two LDS trips are sequential,
//      so each trip gets its OWN pad. Trip 1: pad1(e)=e+(e>>4)
//      (store 8t+k -> p0+k, load t+64k -> l1+68k). Trip 2: pad2(e)=e+8*(e>>6)
//      (store (t&7)+64(t>>3)+8k -> s2+8k with s2=(t&7)+72(t>>3),
//       load t+64k -> t+72k). All four patterns have distinct (elem mod 16)
//      within every 16-lane quarter => conflict-free for 8B/lane ops.

#define R2F 0.70710678118654752f

// 8-point DFT, bins in natural order. Forward = e^{-2pi i/8}; INV conjugates.
template <bool INV>
__device__ __forceinline__ void bfly8(float* xr, float* xi)
{
    float t0r = xr[0] + xr[4], t0i = xi[0] + xi[4];
    float t1r = xr[0] - xr[4], t1i = xi[0] - xi[4];
    float t2r = xr[2] + xr[6], t2i = xi[2] + xi[6];
    float t3r = xr[2] - xr[6], t3i = xi[2] - xi[6];
    float e0r = t0r + t2r, e0i = t0i + t2i;
    float e2r = t0r - t2r, e2i = t0i - t2i;
    float e1r, e1i, e3r, e3i;
    if (!INV) { e1r = t1r + t3i; e1i = t1i - t3r; e3r = t1r - t3i; e3i = t1i + t3r; }
    else      { e1r = t1r - t3i; e1i = t1i + t3r; e3r = t1r + t3i; e3i = t1i - t3r; }
    float s0r = xr[1] + xr[5], s0i = xi[1] + xi[5];
    float s1r = xr[1] - xr[5], s1i = xi[1] - xi[5];
    float s2r = xr[3] + xr[7], s2i = xi[3] + xi[7];
    float s3r = xr[3] - xr[7], s3i = xi[3] - xi[7];
    float o0r = s0r + s2r, o0i = s0i + s2i;
    float o2r = s0r - s2r, o2i = s0i - s2i;
    float o1r, o1i, o3r, o3i;
    if (!INV) { o1r = s1r + s3i; o1i = s1i - s3r; o3r = s1r - s3i; o3i = s1i + s3r; }
    else      { o1r = s1r - s3i; o1i = s1i + s3r; o3r = s1r + s3i; o3i = s1i - s3r; }
    float p1r, p1i, p2r, p2i, p3r, p3i;
    if (!INV) {
        p1r = (o1r + o1i) * R2F;  p1i = (o1i - o1r) * R2F;
        p2r = o2i;                p2i = -o2r;
        p3r = (o3i - o3r) * R2F;  p3i = -(o3r + o3i) * R2F;
    } else {
        p1r = (o1r - o1i) * R2F;  p1i = (o1i + o1r) * R2F;
        p2r = -o2i;               p2i = o2r;
        p3r = -(o3r + o3i) * R2F; p3i = (o3r - o3i) * R2F;
    }
    xr[0] = e0r + o0r; xi[0] = e0i + o0i;
    xr[4] = e0r - o0r; xi[4] = e0i - o0i;
    xr[1] = e1r + p1r; xi[1] = e1i + p1i;
    xr[5] = e1r - p1r; xi[5] = e1i - p1i;
    xr[2] = e2r + p2r; xi[2] = e2i + p2i;
    xr[6] = e2r - p2r; xi[6] = e2i - p2i;
    xr[3] = e3r + p3r; xi[3] = e3i + p3i;
    xr[7] = e3r - p3r; xi[7] = e3i - p3i;
}

// Tables store (cos th, sin th), th >= 0. Forward multiplies by e^{-i th}.
template <bool INV>
__device__ __forceinline__ void tw_apply(float* xr, float* xi,
                                         const float* c, const float* s)
{
#pragma unroll
    for (int k = 1; k < 8; ++k) {
        float r, i;
        if (!INV) { r = xr[k] * c[k] + xi[k] * s[k]; i = xi[k] * c[k] - xr[k] * s[k]; }
        else      { r = xr[k] * c[k] - xi[k] * s[k]; i = xi[k] * c[k] + xr[k] * s[k]; }
        xr[k] = r; xi[k] = i;
    }
}

__global__ __launch_bounds__(256, 4)
void fv_kernel(const float2* __restrict__ x,
               const float2* __restrict__ pq,    // (P[k], q[k]) k=0..511
               const float2* __restrict__ tw1,   // [(k-1)*64 + t], k=1..7
               const float2* __restrict__ tw8,   // [(k-1)*8 + p],  k=1..7
               float2* __restrict__ out)
{
    __shared__ float2 sz[8][568];                // 2 rows per wave, per-trip pads
    const int tid = threadIdx.x;
    const int r = tid >> 6;      // wave id within block
    const int t = tid & 63;      // lane
    float2* shrow[2] = { sz[2 * r], sz[2 * r + 1] };
    const size_t base0 = ((size_t)blockIdx.x * 8 + 2 * r) * 512;  // float2 units

    // twiddle register sets (k=1..7), shared by both rows
    float c1[8], s1[8], c8[8], s8[8];
#pragma unroll
    for (int k = 1; k < 8; ++k) {
        float2 w = tw1[(k - 1) * 64 + t];        c1[k] = w.x; s1[k] = w.y;
        float2 v = tw8[(k - 1) * 8 + (t >> 3)];  c8[k] = v.x; s8[k] = v.y;
    }

    // trip-1 pad: pad1(e)=e+(e>>4)   store 8t+k -> p0+k, load t+64k -> l1+68k
    // trip-2 pad: pad2(e)=e+8*(e>>6) store (t&7)+64(t>>3)+8k -> s2+8k,
    //                                load t+64k -> t+72k
    const int p0 = (t << 3) + (t >> 1);
    const int l1 = t + (t >> 4);
    const int s2 = (t & 7) + 72 * (t >> 3);

    float zr[2][8], zi[2][8];

    // ---- global loads for both rows up front (one vmcnt hides HBM once) ----
#pragma unroll
    for (int rr = 0; rr < 2; ++rr)
#pragma unroll
        for (int k = 0; k < 8; ++k) {
            float2 v = x[base0 + 512 * rr + t + 64 * k];
            zr[rr][k] = v.x; zi[rr][k] = v.y;
        }

    // ---- forward FFT-512, phase-interleaved across the two rows ----
#pragma unroll
    for (int rr = 0; rr < 2; ++rr) {
        bfly8<false>(zr[rr], zi[rr]);
        tw_apply<false>(zr[rr], zi[rr], c1, s1);
        float2* sh = shrow[rr];
#pragma unroll
        for (int k = 0; k < 8; ++k) sh[p0 + k] = make_float2(zr[rr][k], zi[rr][k]);
    }
#pragma unroll
    for (int rr = 0; rr < 2; ++rr) {
        float2* sh = shrow[rr];
#pragma unroll
        for (int k = 0; k < 8; ++k) {
            float2 v = sh[l1 + 68 * k]; zr[rr][k] = v.x; zi[rr][k] = v.y;
        }
    }
#pragma unroll
    for (int rr = 0; rr < 2; ++rr) {
        bfly8<false>(zr[rr], zi[rr]);
        tw_apply<false>(zr[rr], zi[rr], c8, s8);
        float2* sh = shrow[rr];
#pragma unroll
        for (int k = 0; k < 8; ++k) sh[s2 + 8 * k] = make_float2(zr[rr][k], zi[rr][k]);
    }
#pragma unroll
    for (int rr = 0; rr < 2; ++rr) {
        float2* sh = shrow[rr];
#pragma unroll
        for (int k = 0; k < 8; ++k) {
            float2 v = sh[t + 72 * k]; zr[rr][k] = v.x; zi[rr][k] = v.y;
        }
    }

    // ---- stage-3 bfly + combine W = P*Z + i*q*conj(Z_mirror), regs + shfl ----
#pragma unroll
    for (int rr = 0; rr < 2; ++rr) {
        bfly8<false>(zr[rr], zi[rr]);
        const int src = (64 - t) & 63;
        float vr[8], vi[8];
#pragma unroll
        for (int k = 0; k < 8; ++k) {
            vr[k] = __shfl(zr[rr][7 - k], src, 64);
            vi[k] = __shfl(zi[rr][7 - k], src, 64);
        }
        if (t == 0) {
#pragma unroll
            for (int k = 0; k < 8; ++k) {
                int kk = (8 - k) & 7;
                vr[k] = zr[rr][kk]; vi[k] = zi[rr][kk];
            }
        }
#pragma unroll
        for (int k = 0; k < 8; ++k) {
            float2 g = pq[t + 64 * k];
            float nr = g.x * zr[rr][k] + g.y * vi[k];
            float ni = g.x * zi[rr][k] + g.y * vr[k];
            zr[rr][k] = nr; zi[rr][k] = ni;
        }
    }

    // ---- inverse FFT-512 (input already in stage-1 read layout) ----
#pragma unroll
    for (int rr = 0; rr < 2; ++rr) {
        bfly8<true>(zr[rr], zi[rr]);
        tw_apply<true>(zr[rr], zi[rr], c1, s1);
        float2* sh = shrow[rr];
#pragma unroll
        for (int k = 0; k < 8; ++k) sh[p0 + k] = make_float2(zr[rr][k], zi[rr][k]);
    }
#pragma unroll
    for (int rr = 0; rr < 2; ++rr) {
        float2* sh = shrow[rr];
#pragma unroll
        for (int k = 0; k < 8; ++k) {
            float2 v = sh[l1 + 68 * k]; zr[rr][k] = v.x; zi[rr][k] = v.y;
        }
    }
#pragma unroll
    for (int rr = 0; rr < 2; ++rr) {
        bfly8<true>(zr[rr], zi[rr]);
        tw_apply<true>(zr[rr], zi[rr], c8, s8);
        float2* sh = shrow[rr];
#pragma unroll
        for (int k = 0; k < 8; ++k) sh[s2 + 8 * k] = make_float2(zr[rr][k], zi[rr][k]);
    }
#pragma unroll
    for (int rr = 0; rr < 2; ++rr) {
        float2* sh = shrow[rr];
#pragma unroll
        for (int k = 0; k < 8; ++k) {
            float2 v = sh[t + 72 * k]; zr[rr][k] = v.x; zi[rr][k] = v.y;
        }
    }
#pragma unroll
    for (int rr = 0; rr < 2; ++rr) {
        bfly8<true>(zr[rr], zi[rr]);
#pragma unroll
        for (int k = 0; k < 8; ++k)
            out[base0 + 512 * rr + t + 64 * k] = make_float2(zr[rr][k], zi[rr][k]);
    }
}

// Build softmax gate -> (P,q) table and twiddle tables, all in d_ws.
__global__ void gate_kernel(const float* __restrict__ w1,
                            float2* __restrict__ pq,
                            float2* __restrict__ tw1,
                            float2* __restrict__ tw8)
{
    __shared__ float red[1024];
    __shared__ float ex[513];
    const int t = threadIdx.x;  // 1024 threads

    float v = (t < 513) ? w1[t] : -1e30f;
    red[t] = v;
    __syncthreads();
    for (int off = 512; off > 0; off >>= 1) {
        if (t < off) red[t] = fmaxf(red[t], red[t + off]);
        __syncthreads();
    }
    float M = red[0];
    __syncthreads();

    float e = (t < 513) ? expf(w1[t] - M) : 0.0f;
    if (t < 513) ex[t] = e;
    red[t] = e;
    __syncthreads();
    for (int off = 512; off > 0; off >>= 1) {
        if (t < off) red[t] += red[t + off];
        __syncthreads();
    }
    float inv = 1.0f / red[0];
    __syncthreads();

    if (t < 512) {
        float ga = ex[t] * inv;
        float gb = ex[512 - t] * inv;
        float gp = ga + gb, gm = ga - gb;
        float th = (float)t * 6.13592315154256492e-03f;  // pi/512 * t = 2*pi*t/1024
        float sn, cs;
        __sincosf(th, &sn, &cs);
        float P = 0.5f * (gp - gm * sn) * (1.0f / 512.0f);
        float q = 0.5f * (gm * cs) * (1.0f / 512.0f);
        pq[t] = make_float2(P, q);
    }
    if (t < 448) {
        int k = (t >> 6) + 1;
        int j = t & 63;
        float th = (float)(j * k) * 1.22718463151036952e-02f;  // 2*pi/512
        float sn, cs;
        sincosf(th, &sn, &cs);
        tw1[t] = make_float2(cs, sn);
    }
    if (t < 56) {
        int k = (t >> 3) + 1;
        int p = t & 7;
        float th = (float)(p * k) * 9.81747704246810387e-02f;  // 2*pi/64
        float sn, cs;
        sincosf(th, &sn, &cs);
        tw8[t] = make_float2(cs, sn);
    }
}

extern "C" void kernel_launch(void* const* d_in, const int* in_sizes, int n_in,
                              void* d_out, int out_size, void* d_ws, size_t ws_size,
                              hipStream_t stream)
{
    (void)n_in; (void)out_size; (void)ws_size;
    const float2* hidden = (const float2*)d_in[0];   // [32768 rows, 512 float2]
    const float*  w1     = (const float*)d_in[1];    // [513]
    float2* out = (float2*)d_out;

    float2* pq  = (float2*)d_ws;          // 512 float2
    float2* tw1 = pq + 512;               // 448 float2
    float2* tw8 = tw1 + 448;              // 56  float2

    gate_kernel<<<1, 1024, 0, stream>>>(w1, pq, tw1, tw8);

    const int rows   = in_sizes[0] / 1024;   // 32768
    const int blocks = rows / 8;             // 4096 (8 rows per block)
    fv_kernel<<<blocks, 256, 0, stream>>>(hidden, pq, tw1, tw8, out);
}

// Round 3
// 238.892 us; speedup vs baseline: 1.0229x; 1.0229x over previous
//
#include <hip/hip_runtime.h>

// FastVolterra1: out[r,:] = irfft(rfft(x[r,:]) * softmax(w1)), D=1024, fp32.
//
// Real-packed: z[n] = x[2n] + i*x[2n+1] (length 512);
//   Z = FFT_512(z);  W[k] = P[k]*Z[k] + i*q[k]*conj(Z[(512-k)%512]);
//   w = IFFT_512(W); out[2n]=Re w[n], out[2n+1]=Im w[n].
// P,q real, precomputed from softmax gate (1/512 norm folded in).
//
// FFT-512 = 3 radix-8 Stockham stages. 64 threads/row; one row's LDS traffic
// stays within one wave -> NO __syncthreads (same-wave LDS ops are in-order).
//
// R3 (this round): sequential multi-row waves + register prefetch.
// Evidence so far: R1 (32 waves x 1 row) and R2 (16 waves x 2 interleaved
// rows) both hold 32 rows/CU in flight and both run ~81-85us with every pipe
// at 26-35% busy -> throughput = rows_in_flight / per_row_latency. So this
// round attacks BOTH terms without R2's register blow-up (VGPR 64 + 24B/thread
// scratch): each wave processes 4 rows SEQUENTIALLY (grid 2048), prefetching
// row i+1's 8 float2 globals into a named double-buffer while computing row i.
// HBM latency (~900cy) leaves the dependent chain; pq/tw loads are
// loop-invariant and LICM-hoisted into regs. Row loop NOT unrolled (I$ ~6KB);
// cur/nxt named arrays + 16 v_movs keep all indices compile-time (rule #20).
//
// LDS: one 568-float2 buffer per wave (18,176 B/block), dual-pad scheme
// validated conflict-free in R2 (SQ_LDS_BANK_CONFLICT == 0):
//   trip 1: pad1(e)=e+(e>>4)   store 8t+k -> p0+k, load t+64k -> l1+68k
//   trip 2: pad2(e)=e+8*(e>>6) store (t&7)+64(t>>3)+8k -> s2+8k,
//                              load t+64k -> t+72k
// All four patterns have distinct (addr mod 16) within every 16-lane quarter
// => conflict-free for 8B/lane LDS ops.

#define R2F 0.70710678118654752f

// 8-point DFT, bins in natural order. Forward = e^{-2pi i/8}; INV conjugates.
template <bool INV>
__device__ __forceinline__ void bfly8(float* xr, float* xi)
{
    float t0r = xr[0] + xr[4], t0i = xi[0] + xi[4];
    float t1r = xr[0] - xr[4], t1i = xi[0] - xi[4];
    float t2r = xr[2] + xr[6], t2i = xi[2] + xi[6];
    float t3r = xr[2] - xr[6], t3i = xi[2] - xi[6];
    float e0r = t0r + t2r, e0i = t0i + t2i;
    float e2r = t0r - t2r, e2i = t0i - t2i;
    float e1r, e1i, e3r, e3i;
    if (!INV) { e1r = t1r + t3i; e1i = t1i - t3r; e3r = t1r - t3i; e3i = t1i + t3r; }
    else      { e1r = t1r - t3i; e1i = t1i + t3r; e3r = t1r + t3i; e3i = t1i - t3r; }
    float s0r = xr[1] + xr[5], s0i = xi[1] + xi[5];
    float s1r = xr[1] - xr[5], s1i = xi[1] - xi[5];
    float s2r = xr[3] + xr[7], s2i = xi[3] + xi[7];
    float s3r = xr[3] - xr[7], s3i = xi[3] - xi[7];
    float o0r = s0r + s2r, o0i = s0i + s2i;
    float o2r = s0r - s2r, o2i = s0i - s2i;
    float o1r, o1i, o3r, o3i;
    if (!INV) { o1r = s1r + s3i; o1i = s1i - s3r; o3r = s1r - s3i; o3i = s1i + s3r; }
    else      { o1r = s1r - s3i; o1i = s1i + s3r; o3r = s1r + s3i; o3i = s1i - s3r; }
    float p1r, p1i, p2r, p2i, p3r, p3i;
    if (!INV) {
        p1r = (o1r + o1i) * R2F;  p1i = (o1i - o1r) * R2F;
        p2r = o2i;                p2i = -o2r;
        p3r = (o3i - o3r) * R2F;  p3i = -(o3r + o3i) * R2F;
    } else {
        p1r = (o1r - o1i) * R2F;  p1i = (o1i + o1r) * R2F;
        p2r = -o2i;               p2i = o2r;
        p3r = -(o3r + o3i) * R2F; p3i = (o3r - o3i) * R2F;
    }
    xr[0] = e0r + o0r; xi[0] = e0i + o0i;
    xr[4] = e0r - o0r; xi[4] = e0i - o0i;
    xr[1] = e1r + p1r; xi[1] = e1i + p1i;
    xr[5] = e1r - p1r; xi[5] = e1i - p1i;
    xr[2] = e2r + p2r; xi[2] = e2i + p2i;
    xr[6] = e2r - p2r; xi[6] = e2i - p2i;
    xr[3] = e3r + p3r; xi[3] = e3i + p3i;
    xr[7] = e3r - p3r; xi[7] = e3i - p3i;
}

// Tables store (cos th, sin th), th >= 0. Forward multiplies by e^{-i th}.
template <bool INV>
__device__ __forceinline__ void tw_apply(float* xr, float* xi,
                                         const float* c, const float* s)
{
#pragma unroll
    for (int k = 1; k < 8; ++k) {
        float r, i;
        if (!INV) { r = xr[k] * c[k] + xi[k] * s[k]; i = xi[k] * c[k] - xr[k] * s[k]; }
        else      { r = xr[k] * c[k] - xi[k] * s[k]; i = xi[k] * c[k] + xr[k] * s[k]; }
        xr[k] = r; xi[k] = i;
    }
}

#define ROWS_PER_WAVE 4

__global__ __launch_bounds__(256)
void fv_kernel(const float2* __restrict__ x,
               const float2* __restrict__ pq,    // (P[k], q[k]) k=0..511
               const float2* __restrict__ tw1,   // [(k-1)*64 + t], k=1..7
               const float2* __restrict__ tw8,   // [(k-1)*8 + p],  k=1..7
               float2* __restrict__ out)
{
    __shared__ float2 sz[4][568];                // one padded row buffer per wave
    const int tid = threadIdx.x;
    const int r = tid >> 6;      // wave id within block
    const int t = tid & 63;      // lane
    float2* sh = sz[r];
    // wave handles ROWS_PER_WAVE contiguous rows
    const size_t wavebase =
        ((size_t)blockIdx.x * (4 * ROWS_PER_WAVE) + r * ROWS_PER_WAVE) * 512;

    // twiddle register sets (k=1..7), shared by all rows (loop-invariant)
    float c1[8], s1[8], c8[8], s8[8];
#pragma unroll
    for (int k = 1; k < 8; ++k) {
        float2 w = tw1[(k - 1) * 64 + t];        c1[k] = w.x; s1[k] = w.y;
        float2 v = tw8[(k - 1) * 8 + (t >> 3)];  c8[k] = v.x; s8[k] = v.y;
    }

    // trip-1 pad: pad1(e)=e+(e>>4)   store 8t+k -> p0+k, load t+64k -> l1+68k
    // trip-2 pad: pad2(e)=e+8*(e>>6) store (t&7)+64(t>>3)+8k -> s2+8k,
    //                                load t+64k -> t+72k
    const int p0 = (t << 3) + (t >> 1);
    const int l1 = t + (t >> 4);
    const int s2 = (t & 7) + 72 * (t >> 3);

    const int src = (64 - t) & 63;               // mirror shuffle source lane

    // register double-buffer for the global input of the current / next row
    float2 cur[8], nxt[8];
#pragma unroll
    for (int k = 0; k < 8; ++k) cur[k] = x[wavebase + t + 64 * k];

    for (int i = 0; i < ROWS_PER_WAVE; ++i) {
        // ---- prefetch next row's globals (in flight during this row) ----
        if (i < ROWS_PER_WAVE - 1) {
            const size_t nb = wavebase + (size_t)(i + 1) * 512;
#pragma unroll
            for (int k = 0; k < 8; ++k) nxt[k] = x[nb + t + 64 * k];
        }

        float zr[8], zi[8];
#pragma unroll
        for (int k = 0; k < 8; ++k) { zr[k] = cur[k].x; zi[k] = cur[k].y; }

        // ---- forward FFT-512 ----
        bfly8<false>(zr, zi);
        tw_apply<false>(zr, zi, c1, s1);
#pragma unroll
        for (int k = 0; k < 8; ++k) sh[p0 + k] = make_float2(zr[k], zi[k]);
#pragma unroll
        for (int k = 0; k < 8; ++k) {
            float2 v = sh[l1 + 68 * k]; zr[k] = v.x; zi[k] = v.y;
        }
        bfly8<false>(zr, zi);
        tw_apply<false>(zr, zi, c8, s8);
#pragma unroll
        for (int k = 0; k < 8; ++k) sh[s2 + 8 * k] = make_float2(zr[k], zi[k]);
#pragma unroll
        for (int k = 0; k < 8; ++k) {
            float2 v = sh[t + 72 * k]; zr[k] = v.x; zi[k] = v.y;
        }
        bfly8<false>(zr, zi);
        // regs now hold Z[t + 64k] in natural order.

        // ---- combine W = P*Z + i*q*conj(Z_mirror), regs + shfl ----
        {
            float vr[8], vi[8];
#pragma unroll
            for (int k = 0; k < 8; ++k) {
                vr[k] = __shfl(zr[7 - k], src, 64);
                vi[k] = __shfl(zi[7 - k], src, 64);
            }
            if (t == 0) {
#pragma unroll
                for (int k = 0; k < 8; ++k) {
                    int kk = (8 - k) & 7;
                    vr[k] = zr[kk]; vi[k] = zi[kk];
                }
            }
#pragma unroll
            for (int k = 0; k < 8; ++k) {
                float2 g = pq[t + 64 * k];       // loop-invariant -> LICM to regs
                float nr = g.x * zr[k] + g.y * vi[k];
                float ni = g.x * zi[k] + g.y * vr[k];
                zr[k] = nr; zi[k] = ni;
            }
        }

        // ---- inverse FFT-512 (input already in stage-1 read layout) ----
        bfly8<true>(zr, zi);
        tw_apply<true>(zr, zi, c1, s1);
#pragma unroll
        for (int k = 0; k < 8; ++k) sh[p0 + k] = make_float2(zr[k], zi[k]);
#pragma unroll
        for (int k = 0; k < 8; ++k) {
            float2 v = sh[l1 + 68 * k]; zr[k] = v.x; zi[k] = v.y;
        }
        bfly8<true>(zr, zi);
        tw_apply<true>(zr, zi, c8, s8);
#pragma unroll
        for (int k = 0; k < 8; ++k) sh[s2 + 8 * k] = make_float2(zr[k], zi[k]);
#pragma unroll
        for (int k = 0; k < 8; ++k) {
            float2 v = sh[t + 72 * k]; zr[k] = v.x; zi[k] = v.y;
        }
        bfly8<true>(zr, zi);

        // ---- store this row ----
        const size_t ob = wavebase + (size_t)i * 512;
#pragma unroll
        for (int k = 0; k < 8; ++k)
            out[ob + t + 64 * k] = make_float2(zr[k], zi[k]);

        // ---- rotate double-buffer (static indices; 16 v_movs) ----
#pragma unroll
        for (int k = 0; k < 8; ++k) cur[k] = nxt[k];
    }
}

// Build softmax gate -> (P,q) table and twiddle tables, all in d_ws.
__global__ void gate_kernel(const float* __restrict__ w1,
                            float2* __restrict__ pq,
                            float2* __restrict__ tw1,
                            float2* __restrict__ tw8)
{
    __shared__ float red[1024];
    __shared__ float ex[513];
    const int t = threadIdx.x;  // 1024 threads

    float v = (t < 513) ? w1[t] : -1e30f;
    red[t] = v;
    __syncthreads();
    for (int off = 512; off > 0; off >>= 1) {
        if (t < off) red[t] = fmaxf(red[t], red[t + off]);
        __syncthreads();
    }
    float M = red[0];
    __syncthreads();

    float e = (t < 513) ? expf(w1[t] - M) : 0.0f;
    if (t < 513) ex[t] = e;
    red[t] = e;
    __syncthreads();
    for (int off = 512; off > 0; off >>= 1) {
        if (t < off) red[t] += red[t + off];
        __syncthreads();
    }
    float inv = 1.0f / red[0];
    __syncthreads();

    if (t < 512) {
        float ga = ex[t] * inv;
        float gb = ex[512 - t] * inv;
        float gp = ga + gb, gm = ga - gb;
        float th = (float)t * 6.13592315154256492e-03f;  // pi/512 * t = 2*pi*t/1024
        float sn, cs;
        __sincosf(th, &sn, &cs);
        float P = 0.5f * (gp - gm * sn) * (1.0f / 512.0f);
        float q = 0.5f * (gm * cs) * (1.0f / 512.0f);
        pq[t] = make_float2(P, q);
    }
    if (t < 448) {
        int k = (t >> 6) + 1;
        int j = t & 63;
        float th = (float)(j * k) * 1.22718463151036952e-02f;  // 2*pi/512
        float sn, cs;
        sincosf(th, &sn, &cs);
        tw1[t] = make_float2(cs, sn);
    }
    if (t < 56) {
        int k = (t >> 3) + 1;
        int p = t & 7;
        float th = (float)(p * k) * 9.81747704246810387e-02f;  // 2*pi/64
        float sn, cs;
        sincosf(th, &sn, &cs);
        tw8[t] = make_float2(cs, sn);
    }
}

extern "C" void kernel_launch(void* const* d_in, const int* in_sizes, int n_in,
                              void* d_out, int out_size, void* d_ws, size_t ws_size,
                              hipStream_t stream)
{
    (void)n_in; (void)out_size; (void)ws_size;
    const float2* hidden = (const float2*)d_in[0];   // [32768 rows, 512 float2]
    const float*  w1     = (const float*)d_in[1];    // [513]
    float2* out = (float2*)d_out;

    float2* pq  = (float2*)d_ws;          // 512 float2
    float2* tw1 = pq + 512;               // 448 float2
    float2* tw8 = tw1 + 448;              // 56  float2

    gate_kernel<<<1, 1024, 0, stream>>>(w1, pq, tw1, tw8);

    const int rows   = in_sizes[0] / 1024;       // 32768
    const int blocks = rows / (4 * ROWS_PER_WAVE);  // 2048
    fv_kernel<<<blocks, 256, 0, stream>>>(hidden, pq, tw1, tw8, out);
}

// Round 4
// 238.643 us; speedup vs baseline: 1.0239x; 1.0010x over previous
//
#include <hip/hip_runtime.h>

// FastVolterra1: out[r,:] = irfft(rfft(x[r,:]) * softmax(w1)), D=1024, fp32.
//
// Real-packed: z[n] = x[2n] + i*x[2n+1] (length 512);
//   Z = FFT_512(z);  W[k] = P[k]*Z[k] + i*q[k]*conj(Z[(512-k)%512]);
//   w = IFFT_512(W); out[2n]=Re w[n], out[2n+1]=Im w[n].
// P,q real, precomputed from softmax gate (1/512 norm folded in).
//
// FFT-512 = 3 radix-8 Stockham stages. 64 threads/row; one row's LDS traffic
// stays within one wave -> NO __syncthreads (same-wave LDS ops are in-order).
//
// R4 (this round): the CLEAN in-wave-ILP test. History:
//   R1: 32 waves x 1 row          -> 81us, all pipes 26-35%
//   R2: 16 waves x 2 rows ILP     -> 85us, but launch_bounds(256,4) capped
//       VGPR at 64 => 24B/thread scratch (WRITE_SIZE +24576KB) poisoned it
//   R3: 16 waves x 4 seq rows     -> 87us, no spills, prefetch didn't help
// Every pipe sits at 24-35% in all three => latency-bound, wave overlap is
// NOT filling the issue ports. The one untested mechanism: genuine dual
// dependent chains per wave with the allocator UNCONSTRAINED. This is R2
// minus the register cap: plain __launch_bounds__(256) (R3 proved the
// allocator behaves: chose 56 VGPR, zero scratch). Expect ~100 VGPR ->
// 4 waves/SIMD, same as the LDS limit (36,352B/block -> 4 blocks/CU), so
// no occupancy change vs R2/R3 -- isolating the ILP variable.
//
// LDS pads (R2 measured SQ_LDS_BANK_CONFLICT == 0 with exactly these):
//   trip 1: pad1(e)=e+(e>>4)   store 8t+k -> p0+k, load t+64k -> l1+68k
//   trip 2: pad2(e)=e+8*(e>>6) store (t&7)+64(t>>3)+8k -> s2+8k,
//                              load t+64k -> t+72k
// All four patterns have distinct (addr mod 16) within every 16-lane quarter
// => conflict-free for 8B/lane LDS ops.

#define R2F 0.70710678118654752f

// 8-point DFT, bins in natural order. Forward = e^{-2pi i/8}; INV conjugates.
template <bool INV>
__device__ __forceinline__ void bfly8(float* xr, float* xi)
{
    float t0r = xr[0] + xr[4], t0i = xi[0] + xi[4];
    float t1r = xr[0] - xr[4], t1i = xi[0] - xi[4];
    float t2r = xr[2] + xr[6], t2i = xi[2] + xi[6];
    float t3r = xr[2] - xr[6], t3i = xi[2] - xi[6];
    float e0r = t0r + t2r, e0i = t0i + t2i;
    float e2r = t0r - t2r, e2i = t0i - t2i;
    float e1r, e1i, e3r, e3i;
    if (!INV) { e1r = t1r + t3i; e1i = t1i - t3r; e3r = t1r - t3i; e3i = t1i + t3r; }
    else      { e1r = t1r - t3i; e1i = t1i + t3r; e3r = t1r + t3i; e3i = t1i - t3r; }
    float s0r = xr[1] + xr[5], s0i = xi[1] + xi[5];
    float s1r = xr[1] - xr[5], s1i = xi[1] - xi[5];
    float s2r = xr[3] + xr[7], s2i = xi[3] + xi[7];
    float s3r = xr[3] - xr[7], s3i = xi[3] - xi[7];
    float o0r = s0r + s2r, o0i = s0i + s2i;
    float o2r = s0r - s2r, o2i = s0i - s2i;
    float o1r, o1i, o3r, o3i;
    if (!INV) { o1r = s1r + s3i; o1i = s1i - s3r; o3r = s1r - s3i; o3i = s1i + s3r; }
    else      { o1r = s1r - s3i; o1i = s1i + s3r; o3r = s1r + s3i; o3i = s1i - s3r; }
    float p1r, p1i, p2r, p2i, p3r, p3i;
    if (!INV) {
        p1r = (o1r + o1i) * R2F;  p1i = (o1i - o1r) * R2F;
        p2r = o2i;                p2i = -o2r;
        p3r = (o3i - o3r) * R2F;  p3i = -(o3r + o3i) * R2F;
    } else {
        p1r = (o1r - o1i) * R2F;  p1i = (o1i + o1r) * R2F;
        p2r = -o2i;               p2i = o2r;
        p3r = -(o3r + o3i) * R2F; p3i = (o3r - o3i) * R2F;
    }
    xr[0] = e0r + o0r; xi[0] = e0i + o0i;
    xr[4] = e0r - o0r; xi[4] = e0i - o0i;
    xr[1] = e1r + p1r; xi[1] = e1i + p1i;
    xr[5] = e1r - p1r; xi[5] = e1i - p1i;
    xr[2] = e2r + p2r; xi[2] = e2i + p2i;
    xr[6] = e2r - p2r; xi[6] = e2i - p2i;
    xr[3] = e3r + p3r; xi[3] = e3i + p3i;
    xr[7] = e3r - p3r; xi[7] = e3i - p3i;
}

// Tables store (cos th, sin th), th >= 0. Forward multiplies by e^{-i th}.
template <bool INV>
__device__ __forceinline__ void tw_apply(float* xr, float* xi,
                                         const float* c, const float* s)
{
#pragma unroll
    for (int k = 1; k < 8; ++k) {
        float r, i;
        if (!INV) { r = xr[k] * c[k] + xi[k] * s[k]; i = xi[k] * c[k] - xr[k] * s[k]; }
        else      { r = xr[k] * c[k] - xi[k] * s[k]; i = xi[k] * c[k] + xr[k] * s[k]; }
        xr[k] = r; xi[k] = i;
    }
}

__global__ __launch_bounds__(256)
void fv_kernel(const float2* __restrict__ x,
               const float2* __restrict__ pq,    // (P[k], q[k]) k=0..511
               const float2* __restrict__ tw1,   // [(k-1)*64 + t], k=1..7
               const float2* __restrict__ tw8,   // [(k-1)*8 + p],  k=1..7
               float2* __restrict__ out)
{
    __shared__ float2 sz[8][568];                // 2 row-buffers per wave
    const int tid = threadIdx.x;
    const int r = tid >> 6;      // wave id within block
    const int t = tid & 63;      // lane
    float2* shrow[2] = { sz[2 * r], sz[2 * r + 1] };
    const size_t base0 = ((size_t)blockIdx.x * 8 + 2 * r) * 512;  // float2 units

    // twiddle register sets (k=1..7), shared by both rows
    float c1[8], s1[8], c8[8], s8[8];
#pragma unroll
    for (int k = 1; k < 8; ++k) {
        float2 w = tw1[(k - 1) * 64 + t];        c1[k] = w.x; s1[k] = w.y;
        float2 v = tw8[(k - 1) * 8 + (t >> 3)];  c8[k] = v.x; s8[k] = v.y;
    }

    // trip-1 pad: pad1(e)=e+(e>>4)   store 8t+k -> p0+k, load t+64k -> l1+68k
    // trip-2 pad: pad2(e)=e+8*(e>>6) store (t&7)+64(t>>3)+8k -> s2+8k,
    //                                load t+64k -> t+72k
    const int p0 = (t << 3) + (t >> 1);
    const int l1 = t + (t >> 4);
    const int s2 = (t & 7) + 72 * (t >> 3);

    float zr[2][8], zi[2][8];

    // ---- global loads for both rows up front (one vmcnt hides HBM once) ----
#pragma unroll
    for (int rr = 0; rr < 2; ++rr)
#pragma unroll
        for (int k = 0; k < 8; ++k) {
            float2 v = x[base0 + 512 * rr + t + 64 * k];
            zr[rr][k] = v.x; zi[rr][k] = v.y;
        }

    // ---- forward FFT-512, phase-interleaved across the two rows ----
#pragma unroll
    for (int rr = 0; rr < 2; ++rr) {
        bfly8<false>(zr[rr], zi[rr]);
        tw_apply<false>(zr[rr], zi[rr], c1, s1);
        float2* sh = shrow[rr];
#pragma unroll
        for (int k = 0; k < 8; ++k) sh[p0 + k] = make_float2(zr[rr][k], zi[rr][k]);
    }
#pragma unroll
    for (int rr = 0; rr < 2; ++rr) {
        float2* sh = shrow[rr];
#pragma unroll
        for (int k = 0; k < 8; ++k) {
            float2 v = sh[l1 + 68 * k]; zr[rr][k] = v.x; zi[rr][k] = v.y;
        }
    }
#pragma unroll
    for (int rr = 0; rr < 2; ++rr) {
        bfly8<false>(zr[rr], zi[rr]);
        tw_apply<false>(zr[rr], zi[rr], c8, s8);
        float2* sh = shrow[rr];
#pragma unroll
        for (int k = 0; k < 8; ++k) sh[s2 + 8 * k] = make_float2(zr[rr][k], zi[rr][k]);
    }
#pragma unroll
    for (int rr = 0; rr < 2; ++rr) {
        float2* sh = shrow[rr];
#pragma unroll
        for (int k = 0; k < 8; ++k) {
            float2 v = sh[t + 72 * k]; zr[rr][k] = v.x; zi[rr][k] = v.y;
        }
    }

    // ---- stage-3 bfly + combine W = P*Z + i*q*conj(Z_mirror), regs + shfl ----
#pragma unroll
    for (int rr = 0; rr < 2; ++rr) {
        bfly8<false>(zr[rr], zi[rr]);
        const int src = (64 - t) & 63;
        float vr[8], vi[8];
#pragma unroll
        for (int k = 0; k < 8; ++k) {
            vr[k] = __shfl(zr[rr][7 - k], src, 64);
            vi[k] = __shfl(zi[rr][7 - k], src, 64);
        }
        if (t == 0) {
#pragma unroll
            for (int k = 0; k < 8; ++k) {
                int kk = (8 - k) & 7;
                vr[k] = zr[rr][kk]; vi[k] = zi[rr][kk];
            }
        }
#pragma unroll
        for (int k = 0; k < 8; ++k) {
            float2 g = pq[t + 64 * k];
            float nr = g.x * zr[rr][k] + g.y * vi[k];
            float ni = g.x * zi[rr][k] + g.y * vr[k];
            zr[rr][k] = nr; zi[rr][k] = ni;
        }
    }

    // ---- inverse FFT-512 (input already in stage-1 read layout) ----
#pragma unroll
    for (int rr = 0; rr < 2; ++rr) {
        bfly8<true>(zr[rr], zi[rr]);
        tw_apply<true>(zr[rr], zi[rr], c1, s1);
        float2* sh = shrow[rr];
#pragma unroll
        for (int k = 0; k < 8; ++k) sh[p0 + k] = make_float2(zr[rr][k], zi[rr][k]);
    }
#pragma unroll
    for (int rr = 0; rr < 2; ++rr) {
        float2* sh = shrow[rr];
#pragma unroll
        for (int k = 0; k < 8; ++k) {
            float2 v = sh[l1 + 68 * k]; zr[rr][k] = v.x; zi[rr][k] = v.y;
        }
    }
#pragma unroll
    for (int rr = 0; rr < 2; ++rr) {
        bfly8<true>(zr[rr], zi[rr]);
        tw_apply<true>(zr[rr], zi[rr], c8, s8);
        float2* sh = shrow[rr];
#pragma unroll
        for (int k = 0; k < 8; ++k) sh[s2 + 8 * k] = make_float2(zr[rr][k], zi[rr][k]);
    }
#pragma unroll
    for (int rr = 0; rr < 2; ++rr) {
        float2* sh = shrow[rr];
#pragma unroll
        for (int k = 0; k < 8; ++k) {
            float2 v = sh[t + 72 * k]; zr[rr][k] = v.x; zi[rr][k] = v.y;
        }
    }
#pragma unroll
    for (int rr = 0; rr < 2; ++rr) {
        bfly8<true>(zr[rr], zi[rr]);
#pragma unroll
        for (int k = 0; k < 8; ++k)
            out[base0 + 512 * rr + t + 64 * k] = make_float2(zr[rr][k], zi[rr][k]);
    }
}

// Build softmax gate -> (P,q) table and twiddle tables, all in d_ws.
__global__ void gate_kernel(const float* __restrict__ w1,
                            float2* __restrict__ pq,
                            float2* __restrict__ tw1,
                            float2* __restrict__ tw8)
{
    __shared__ float red[1024];
    __shared__ float ex[513];
    const int t = threadIdx.x;  // 1024 threads

    float v = (t < 513) ? w1[t] : -1e30f;
    red[t] = v;
    __syncthreads();
    for (int off = 512; off > 0; off >>= 1) {
        if (t < off) red[t] = fmaxf(red[t], red[t + off]);
        __syncthreads();
    }
    float M = red[0];
    __syncthreads();

    float e = (t < 513) ? expf(w1[t] - M) : 0.0f;
    if (t < 513) ex[t] = e;
    red[t] = e;
    __syncthreads();
    for (int off = 512; off > 0; off >>= 1) {
        if (t < off) red[t] += red[t + off];
        __syncthreads();
    }
    float inv = 1.0f / red[0];
    __syncthreads();

    if (t < 512) {
        float ga = ex[t] * inv;
        float gb = ex[512 - t] * inv;
        float gp = ga + gb, gm = ga - gb;
        float th = (float)t * 6.13592315154256492e-03f;  // pi/512 * t = 2*pi*t/1024
        float sn, cs;
        __sincosf(th, &sn, &cs);
        float P = 0.5f * (gp - gm * sn) * (1.0f / 512.0f);
        float q = 0.5f * (gm * cs) * (1.0f / 512.0f);
        pq[t] = make_float2(P, q);
    }
    if (t < 448) {
        int k = (t >> 6) + 1;
        int j = t & 63;
        float th = (float)(j * k) * 1.22718463151036952e-02f;  // 2*pi/512
        float sn, cs;
        sincosf(th, &sn, &cs);
        tw1[t] = make_float2(cs, sn);
    }
    if (t < 56) {
        int k = (t >> 3) + 1;
        int p = t & 7;
        float th = (float)(p * k) * 9.81747704246810387e-02f;  // 2*pi/64
        float sn, cs;
        sincosf(th, &sn, &cs);
        tw8[t] = make_float2(cs, sn);
    }
}

extern "C" void kernel_launch(void* const* d_in, const int* in_sizes, int n_in,
                              void* d_out, int out_size, void* d_ws, size_t ws_size,
                              hipStream_t stream)
{
    (void)n_in; (void)out_size; (void)ws_size;
    const float2* hidden = (const float2*)d_in[0];   // [32768 rows, 512 float2]
    const float*  w1     = (const float*)d_in[1];    // [513]
    float2* out = (float2*)d_out;

    float2* pq  = (float2*)d_ws;          // 512 float2
    float2* tw1 = pq + 512;               // 448 float2
    float2* tw8 = tw1 + 448;              // 56  float2

    gate_kernel<<<1, 1024, 0, stream>>>(w1, pq, tw1, tw8);

    const int rows   = in_sizes[0] / 1024;   // 32768
    const int blocks = rows / 8;             // 4096 (8 rows per block)
    fv_kernel<<<blocks, 256, 0, stream>>>(hidden, pq, tw1, tw8, out);
}

// Round 5
// 236.449 us; speedup vs baseline: 1.0334x; 1.0093x over previous
//
#include <hip/hip_runtime.h>

// FastVolterra1: out[r,:] = irfft(rfft(x[r,:]) * softmax(w1)), D=1024, fp32.
//
// Real-packed: z[n] = x[2n] + i*x[2n+1] (length 512);
//   Z = FFT_512(z);  W[k] = P[k]*Z[k] + i*q[k]*conj(Z[(512-k)%512]);
//   w = IFFT_512(W); out[2n]=Re w[n], out[2n+1]=Im w[n].
// P,q real, precomputed from softmax gate (1/512 norm folded in).
//
// FFT-512 = 3 radix-8 Stockham stages. 64 threads/row; wave-local LDS ->
// NO __syncthreads (same-wave LDS ops are in-order; validated R1-R4).
//
// R5: LDS WAVE-OP COUNT is the theory. R1-R4 tried 4 concurrency/ILP
// structures (1row, 2row-ILP(spilled), 4row-prefetch, 2row-ILP(clean)):
// ALL land 81-87us, all pipes "30%". Only consistent model: LDS pipe at
// ~15-18 cyc effective per wave-op -> 80 ops/row x 18 ~= the entire 1519
// cyc/row/CU budget -> LDS pipe ~saturated (the 30% estimate came from an
// unmeasured 6cyc/op assumption). Fix + discriminating test in one:
//  (a) fuse the 2 rows into each LDS op: float4 = (Ar,Ai,Br,Bi), ds_*_b128.
//      Transpose ops per row: 64 -> 32. Bytes unchanged (byte-limited null).
//  (b) mirror via LDS (8 b128 writes + 8 reads per pair = 8/row) replaces
//      16 ds_bpermute/row AND the divergent t==0 branch.
//  Total: 80 -> 40 wave-ops/row at constant bytes.
// Single pad for b128: pad(e) = e + (e>>3), buffer 576 float4/wave.
//   store1 8t+k        -> 9t+k          : mod8 = (t+k)&7      distinct/cluster
//   load   t+64k       -> t+(t>>3)+72k  : mod8 = (t+c)&7      distinct
//   store2 (t&7)+64(t>>3)+8k -> (t&7)+72(t>>3)+9k : (t&7+k)&7 distinct
//   mirror read pad((512-t-64k)&511): one 2-way per cluster (free, m136).
// pq loads hoisted to kernel start (latency hides under fwd FFT).
// LDS 4 x 576 x 16B = 36,864 B/block -> 4 blocks/CU (unchanged occupancy).

#define R2F 0.70710678118654752f

// 8-point DFT, bins in natural order. Forward = e^{-2pi i/8}; INV conjugates.
template <bool INV>
__device__ __forceinline__ void bfly8(float* xr, float* xi)
{
    float t0r = xr[0] + xr[4], t0i = xi[0] + xi[4];
    float t1r = xr[0] - xr[4], t1i = xi[0] - xi[4];
    float t2r = xr[2] + xr[6], t2i = xi[2] + xi[6];
    float t3r = xr[2] - xr[6], t3i = xi[2] - xi[6];
    float e0r = t0r + t2r, e0i = t0i + t2i;
    float e2r = t0r - t2r, e2i = t0i - t2i;
    float e1r, e1i, e3r, e3i;
    if (!INV) { e1r = t1r + t3i; e1i = t1i - t3r; e3r = t1r - t3i; e3i = t1i + t3r; }
    else      { e1r = t1r - t3i; e1i = t1i + t3r; e3r = t1r + t3i; e3i = t1i - t3r; }
    float s0r = xr[1] + xr[5], s0i = xi[1] + xi[5];
    float s1r = xr[1] - xr[5], s1i = xi[1] - xi[5];
    float s2r = xr[3] + xr[7], s2i = xi[3] + xi[7];
    float s3r = xr[3] - xr[7], s3i = xi[3] - xi[7];
    float o0r = s0r + s2r, o0i = s0i + s2i;
    float o2r = s0r - s2r, o2i = s0i - s2i;
    float o1r, o1i, o3r, o3i;
    if (!INV) { o1r = s1r + s3i; o1i = s1i - s3r; o3r = s1r - s3i; o3i = s1i + s3r; }
    else      { o1r = s1r - s3i; o1i = s1i + s3r; o3r = s1r + s3i; o3i = s1i - s3r; }
    float p1r, p1i, p2r, p2i, p3r, p3i;
    if (!INV) {
        p1r = (o1r + o1i) * R2F;  p1i = (o1i - o1r) * R2F;
        p2r = o2i;                p2i = -o2r;
        p3r = (o3i - o3r) * R2F;  p3i = -(o3r + o3i) * R2F;
    } else {
        p1r = (o1r - o1i) * R2F;  p1i = (o1i + o1r) * R2F;
        p2r = -o2i;               p2i = o2r;
        p3r = -(o3r + o3i) * R2F; p3i = (o3r - o3i) * R2F;
    }
    xr[0] = e0r + o0r; xi[0] = e0i + o0i;
    xr[4] = e0r - o0r; xi[4] = e0i - o0i;
    xr[1] = e1r + p1r; xi[1] = e1i + p1i;
    xr[5] = e1r - p1r; xi[5] = e1i - p1i;
    xr[2] = e2r + p2r; xi[2] = e2i + p2i;
    xr[6] = e2r - p2r; xi[6] = e2i - p2i;
    xr[3] = e3r + p3r; xi[3] = e3i + p3i;
    xr[7] = e3r - p3r; xi[7] = e3i - p3i;
}

// Tables store (cos th, sin th), th >= 0. Forward multiplies by e^{-i th}.
template <bool INV>
__device__ __forceinline__ void tw_apply(float* xr, float* xi,
                                         const float* c, const float* s)
{
#pragma unroll
    for (int k = 1; k < 8; ++k) {
        float r, i;
        if (!INV) { r = xr[k] * c[k] + xi[k] * s[k]; i = xi[k] * c[k] - xr[k] * s[k]; }
        else      { r = xr[k] * c[k] - xi[k] * s[k]; i = xi[k] * c[k] + xr[k] * s[k]; }
        xr[k] = r; xi[k] = i;
    }
}

__global__ __launch_bounds__(256)
void fv_kernel(const float2* __restrict__ x,
               const float2* __restrict__ pq,    // (P[k], q[k]) k=0..511
               const float2* __restrict__ tw1,   // [(k-1)*64 + t], k=1..7
               const float2* __restrict__ tw8,   // [(k-1)*8 + p],  k=1..7
               float2* __restrict__ out)
{
    __shared__ float4 sb4[4][576];               // (Ar,Ai,Br,Bi), pad(e)=e+(e>>3)
    const int tid = threadIdx.x;
    const int r = tid >> 6;      // wave id within block
    const int t = tid & 63;      // lane
    float4* buf = sb4[r];
    const size_t baseA = ((size_t)blockIdx.x * 8 + 2 * r) * 512;  // float2 units
    const size_t baseB = baseA + 512;

    // twiddle register sets (k=1..7), shared by both rows
    float c1[8], s1[8], c8[8], s8[8];
#pragma unroll
    for (int k = 1; k < 8; ++k) {
        float2 w = tw1[(k - 1) * 64 + t];        c1[k] = w.x; s1[k] = w.y;
        float2 v = tw8[(k - 1) * 8 + (t >> 3)];  c8[k] = v.x; s8[k] = v.y;
    }

    // padded addresses (float4 units), pad(e) = e + (e>>3):
    const int st1 = 9 * t;                   // + k
    const int ld0 = t + (t >> 3);            // + 72*k   (== pad(t+64k))
    const int st2 = (t & 7) + 72 * (t >> 3); // + 9*k

    float ar[8], ai[8], br[8], bi[8];
    float pqx[8], pqy[8];

    // ---- hoisted pq loads (latency hides under forward FFT) ----
#pragma unroll
    for (int k = 0; k < 8; ++k) {
        float2 g = pq[t + 64 * k];
        pqx[k] = g.x; pqy[k] = g.y;
    }

    // ---- global loads, both rows ----
#pragma unroll
    for (int k = 0; k < 8; ++k) {
        float2 v = x[baseA + t + 64 * k];
        ar[k] = v.x; ai[k] = v.y;
    }
#pragma unroll
    for (int k = 0; k < 8; ++k) {
        float2 v = x[baseB + t + 64 * k];
        br[k] = v.x; bi[k] = v.y;
    }

    // ---- forward FFT-512 (both rows share every LDS op) ----
    bfly8<false>(ar, ai); tw_apply<false>(ar, ai, c1, s1);
    bfly8<false>(br, bi); tw_apply<false>(br, bi, c1, s1);
#pragma unroll
    for (int k = 0; k < 8; ++k) buf[st1 + k] = make_float4(ar[k], ai[k], br[k], bi[k]);
#pragma unroll
    for (int k = 0; k < 8; ++k) {
        float4 v = buf[ld0 + 72 * k];
        ar[k] = v.x; ai[k] = v.y; br[k] = v.z; bi[k] = v.w;
    }
    bfly8<false>(ar, ai); tw_apply<false>(ar, ai, c8, s8);
    bfly8<false>(br, bi); tw_apply<false>(br, bi, c8, s8);
#pragma unroll
    for (int k = 0; k < 8; ++k) buf[st2 + 9 * k] = make_float4(ar[k], ai[k], br[k], bi[k]);
#pragma unroll
    for (int k = 0; k < 8; ++k) {
        float4 v = buf[ld0 + 72 * k];
        ar[k] = v.x; ai[k] = v.y; br[k] = v.z; bi[k] = v.w;
    }
    bfly8<false>(ar, ai);
    bfly8<false>(br, bi);
    // regs now hold Z[t + 64k] in natural order (both rows).

    // ---- mirror via LDS: write Z at pad(e), read pad((512-e)&511) ----
#pragma unroll
    for (int k = 0; k < 8; ++k) buf[ld0 + 72 * k] = make_float4(ar[k], ai[k], br[k], bi[k]);
#pragma unroll
    for (int k = 0; k < 8; ++k) {
        int m = (512 - (t + 64 * k)) & 511;
        float4 v = buf[m + (m >> 3)];        // (ArM, AiM, BrM, BiM)
        // W = P*Z + i*q*conj(Zm):  nr = P*zr + q*Im(Zm), ni = P*zi + q*Re(Zm)
        float nrA = pqx[k] * ar[k] + pqy[k] * v.y;
        float niA = pqx[k] * ai[k] + pqy[k] * v.x;
        float nrB = pqx[k] * br[k] + pqy[k] * v.w;
        float niB = pqx[k] * bi[k] + pqy[k] * v.z;
        ar[k] = nrA; ai[k] = niA; br[k] = nrB; bi[k] = niB;
    }

    // ---- inverse FFT-512 (input already in stage-1 read layout) ----
    bfly8<true>(ar, ai); tw_apply<true>(ar, ai, c1, s1);
    bfly8<true>(br, bi); tw_apply<true>(br, bi, c1, s1);
#pragma unroll
    for (int k = 0; k < 8; ++k) buf[st1 + k] = make_float4(ar[k], ai[k], br[k], bi[k]);
#pragma unroll
    for (int k = 0; k < 8; ++k) {
        float4 v = buf[ld0 + 72 * k];
        ar[k] = v.x; ai[k] = v.y; br[k] = v.z; bi[k] = v.w;
    }
    bfly8<true>(ar, ai); tw_apply<true>(ar, ai, c8, s8);
    bfly8<true>(br, bi); tw_apply<true>(br, bi, c8, s8);
#pragma unroll
    for (int k = 0; k < 8; ++k) buf[st2 + 9 * k] = make_float4(ar[k], ai[k], br[k], bi[k]);
#pragma unroll
    for (int k = 0; k < 8; ++k) {
        float4 v = buf[ld0 + 72 * k];
        ar[k] = v.x; ai[k] = v.y; br[k] = v.z; bi[k] = v.w;
    }
    bfly8<true>(ar, ai);
    bfly8<true>(br, bi);

    // ---- stores, both rows ----
#pragma unroll
    for (int k = 0; k < 8; ++k)
        out[baseA + t + 64 * k] = make_float2(ar[k], ai[k]);
#pragma unroll
    for (int k = 0; k < 8; ++k)
        out[baseB + t + 64 * k] = make_float2(br[k], bi[k]);
}

// Build softmax gate -> (P,q) table and twiddle tables, all in d_ws.
__global__ void gate_kernel(const float* __restrict__ w1,
                            float2* __restrict__ pq,
                            float2* __restrict__ tw1,
                            float2* __restrict__ tw8)
{
    __shared__ float red[1024];
    __shared__ float ex[513];
    const int t = threadIdx.x;  // 1024 threads

    float v = (t < 513) ? w1[t] : -1e30f;
    red[t] = v;
    __syncthreads();
    for (int off = 512; off > 0; off >>= 1) {
        if (t < off) red[t] = fmaxf(red[t], red[t + off]);
        __syncthreads();
    }
    float M = red[0];
    __syncthreads();

    float e = (t < 513) ? expf(w1[t] - M) : 0.0f;
    if (t < 513) ex[t] = e;
    red[t] = e;
    __syncthreads();
    for (int off = 512; off > 0; off >>= 1) {
        if (t < off) red[t] += red[t + off];
        __syncthreads();
    }
    float inv = 1.0f / red[0];
    __syncthreads();

    if (t < 512) {
        float ga = ex[t] * inv;
        float gb = ex[512 - t] * inv;
        float gp = ga + gb, gm = ga - gb;
        float th = (float)t * 6.13592315154256492e-03f;  // pi/512 * t = 2*pi*t/1024
        float sn, cs;
        __sincosf(th, &sn, &cs);
        float P = 0.5f * (gp - gm * sn) * (1.0f / 512.0f);
        float q = 0.5f * (gm * cs) * (1.0f / 512.0f);
        pq[t] = make_float2(P, q);
    }
    if (t < 448) {
        int k = (t >> 6) + 1;
        int j = t & 63;
        float th = (float)(j * k) * 1.22718463151036952e-02f;  // 2*pi/512
        float sn, cs;
        sincosf(th, &sn, &cs);
        tw1[t] = make_float2(cs, sn);
    }
    if (t < 56) {
        int k = (t >> 3) + 1;
        int p = t & 7;
        float th = (float)(p * k) * 9.81747704246810387e-02f;  // 2*pi/64
        float sn, cs;
        sincosf(th, &sn, &cs);
        tw8[t] = make_float2(cs, sn);
    }
}

extern "C" void kernel_launch(void* const* d_in, const int* in_sizes, int n_in,
                              void* d_out, int out_size, void* d_ws, size_t ws_size,
                              hipStream_t stream)
{
    (void)n_in; (void)out_size; (void)ws_size;
    const float2* hidden = (const float2*)d_in[0];   // [32768 rows, 512 float2]
    const float*  w1     = (const float*)d_in[1];    // [513]
    float2* out = (float2*)d_out;

    float2* pq  = (float2*)d_ws;          // 512 float2
    float2* tw1 = pq + 512;               // 448 float2
    float2* tw8 = tw1 + 448;              // 56  float2

    gate_kernel<<<1, 1024, 0, stream>>>(w1, pq, tw1, tw8);

    const int rows   = in_sizes[0] / 1024;   // 32768
    const int blocks = rows / 8;             // 4096 (8 rows per block, 2/wave)
    fv_kernel<<<blocks, 256, 0, stream>>>(hidden, pq, tw1, tw8, out);
}

// Round 6
// 235.757 us; speedup vs baseline: 1.0365x; 1.0029x over previous
//
#include <hip/hip_runtime.h>

// FastVolterra1: out[r,:] = irfft(rfft(x[r,:]) * softmax(w1)), D=1024, fp32.
//
// Real-packed: z[n] = x[2n] + i*x[2n+1] (length 512);
//   Z = FFT_512(z);  W[k] = P[k]*Z[k] + i*q[k]*conj(Z[(512-k)%512]);
//   w = IFFT_512(W); out[2n]=Re w[n], out[2n+1]=Im w[n].
// P,q real, precomputed from softmax gate (1/512 norm folded in).
//
// FFT-512 = 3 radix-8 Stockham stages; 64 lanes/row, 2 rows fused per wave
// (float4 LDS = (Ar,Ai,Br,Bi)); wave-local LDS -> NO __syncthreads.
//
// R6: VMEM-INSTRUCTION-COUNT theory. Ledger of falsified levers (all pinned
// at 81+-3us, every pipe <35%): concurrency structure (R1-R4), in-wave ILP
// (R4), prefetch (R3), occupancy 10-14 waves/CU, LDS op count 80<->40/pair
// (R5), conflicts 0<->7M (R1/R4/R5). Budget: 12.1k cyc/pair, ~3k VALU issue,
// <0.5k LDS pipe, ~9k exposed waits. Only never-varied class: VMEM count
// (~54 instrs/pair at 8B/lane). At ~200cyc exposed each (thin 2.6 waves/SIMD
// residency can't hide L2/TA processing), 54 x 200 ~= the 9k residual.
// Change: dwordx4 x-loads and out-stores (16B/lane) via an entry/exit LDS
// bounce (load bins {2t+128j,+1} as float4, pair A/B in regs, b128 store at
// pad(bin), b128 read at pad(t+64k) -> FFT body BIT-IDENTICAL to R5).
// x+out VMEM 32 -> 16 instrs/pair at constant bytes. LDS 80 -> 112 ops/pair:
// spending the proven-free resource (LDS ~5% busy) to buy the suspect one.
// Bank check (b128, 8-lane cluster, mod 8): bounce addr 2t+128j+pad ->
// {0,2,4,6,1,3,5,7} distinct; odd-bin +1 distinct; ld0+72k validated.
// Falsifier: fv >= 75us kills the last throughput theory -> declare floor.
//
// pad(e) = e + (e>>3), buffer 576 float4/wave (36,864 B/block, 4 blocks/CU).

#define R2F 0.70710678118654752f

// 8-point DFT, bins in natural order. Forward = e^{-2pi i/8}; INV conjugates.
template <bool INV>
__device__ __forceinline__ void bfly8(float* xr, float* xi)
{
    float t0r = xr[0] + xr[4], t0i = xi[0] + xi[4];
    float t1r = xr[0] - xr[4], t1i = xi[0] - xi[4];
    float t2r = xr[2] + xr[6], t2i = xi[2] + xi[6];
    float t3r = xr[2] - xr[6], t3i = xi[2] - xi[6];
    float e0r = t0r + t2r, e0i = t0i + t2i;
    float e2r = t0r - t2r, e2i = t0i - t2i;
    float e1r, e1i, e3r, e3i;
    if (!INV) { e1r = t1r + t3i; e1i = t1i - t3r; e3r = t1r - t3i; e3i = t1i + t3r; }
    else      { e1r = t1r - t3i; e1i = t1i + t3r; e3r = t1r + t3i; e3i = t1i - t3r; }
    float s0r = xr[1] + xr[5], s0i = xi[1] + xi[5];
    float s1r = xr[1] - xr[5], s1i = xi[1] - xi[5];
    float s2r = xr[3] + xr[7], s2i = xi[3] + xi[7];
    float s3r = xr[3] - xr[7], s3i = xi[3] - xi[7];
    float o0r = s0r + s2r, o0i = s0i + s2i;
    float o2r = s0r - s2r, o2i = s0i - s2i;
    float o1r, o1i, o3r, o3i;
    if (!INV) { o1r = s1r + s3i; o1i = s1i - s3r; o3r = s1r - s3i; o3i = s1i + s3r; }
    else      { o1r = s1r - s3i; o1i = s1i + s3r; o3r = s1r + s3i; o3i = s1i - s3r; }
    float p1r, p1i, p2r, p2i, p3r, p3i;
    if (!INV) {
        p1r = (o1r + o1i) * R2F;  p1i = (o1i - o1r) * R2F;
        p2r = o2i;                p2i = -o2r;
        p3r = (o3i - o3r) * R2F;  p3i = -(o3r + o3i) * R2F;
    } else {
        p1r = (o1r - o1i) * R2F;  p1i = (o1i + o1r) * R2F;
        p2r = -o2i;               p2i = o2r;
        p3r = -(o3r + o3i) * R2F; p3i = (o3r - o3i) * R2F;
    }
    xr[0] = e0r + o0r; xi[0] = e0i + o0i;
    xr[4] = e0r - o0r; xi[4] = e0i - o0i;
    xr[1] = e1r + p1r; xi[1] = e1i + p1i;
    xr[5] = e1r - p1r; xi[5] = e1i - p1i;
    xr[2] = e2r + p2r; xi[2] = e2i + p2i;
    xr[6] = e2r - p2r; xi[6] = e2i - p2i;
    xr[3] = e3r + p3r; xi[3] = e3i + p3i;
    xr[7] = e3r - p3r; xi[7] = e3i - p3i;
}

// Tables store (cos th, sin th), th >= 0. Forward multiplies by e^{-i th}.
template <bool INV>
__device__ __forceinline__ void tw_apply(float* xr, float* xi,
                                         const float* c, const float* s)
{
#pragma unroll
    for (int k = 1; k < 8; ++k) {
        float r, i;
        if (!INV) { r = xr[k] * c[k] + xi[k] * s[k]; i = xi[k] * c[k] - xr[k] * s[k]; }
        else      { r = xr[k] * c[k] - xi[k] * s[k]; i = xi[k] * c[k] + xr[k] * s[k]; }
        xr[k] = r; xi[k] = i;
    }
}

__global__ __launch_bounds__(256)
void fv_kernel(const float4* __restrict__ x4,   // rows as 256 float4
               const float2* __restrict__ pq,    // (P[k], q[k]) k=0..511
               const float2* __restrict__ tw1,   // [(k-1)*64 + t], k=1..7
               const float2* __restrict__ tw8,   // [(k-1)*8 + p],  k=1..7
               float4* __restrict__ out4)
{
    __shared__ float4 sb4[4][576];               // (Ar,Ai,Br,Bi), pad(e)=e+(e>>3)
    const int tid = threadIdx.x;
    const int r = tid >> 6;      // wave id within block
    const int t = tid & 63;      // lane
    float4* buf = sb4[r];
    const size_t baseA4 = ((size_t)blockIdx.x * 8 + 2 * r) * 256;  // float4 units
    const size_t baseB4 = baseA4 + 256;

    // ---- dwordx4 global loads: 4 per row (bins 2t+128j, 2t+128j+1) ----
    float4 la[4], lb[4];
#pragma unroll
    for (int j = 0; j < 4; ++j) la[j] = x4[baseA4 + t + 64 * j];
#pragma unroll
    for (int j = 0; j < 4; ++j) lb[j] = x4[baseB4 + t + 64 * j];

    // twiddle + pq register sets (latency hides under the x wait)
    float c1[8], s1[8], c8[8], s8[8];
#pragma unroll
    for (int k = 1; k < 8; ++k) {
        float2 w = tw1[(k - 1) * 64 + t];        c1[k] = w.x; s1[k] = w.y;
        float2 v = tw8[(k - 1) * 8 + (t >> 3)];  c8[k] = v.x; s8[k] = v.y;
    }
    float pqx[8], pqy[8];
#pragma unroll
    for (int k = 0; k < 8; ++k) {
        float2 g = pq[t + 64 * k];
        pqx[k] = g.x; pqy[k] = g.y;
    }

    // padded addresses (float4 units), pad(e) = e + (e>>3):
    const int st1 = 9 * t;                   // + k
    const int ld0 = t + (t >> 3);            // + 72*k   (== pad(t+64k))
    const int st2 = (t & 7) + 72 * (t >> 3); // + 9*k

    // ---- entry bounce: pair A/B per bin, store at pad(bin), read natural ----
#pragma unroll
    for (int j = 0; j < 4; ++j) {
        int b0 = 2 * t + 128 * j;            // even bin (b0 mod 8 is even)
        int a0 = b0 + (b0 >> 3);
        buf[a0]     = make_float4(la[j].x, la[j].y, lb[j].x, lb[j].y);
        buf[a0 + 1] = make_float4(la[j].z, la[j].w, lb[j].z, lb[j].w);
    }
    float ar[8], ai[8], br[8], bi[8];
#pragma unroll
    for (int k = 0; k < 8; ++k) {
        float4 v = buf[ld0 + 72 * k];
        ar[k] = v.x; ai[k] = v.y; br[k] = v.z; bi[k] = v.w;
    }

    // ---- forward FFT-512 (both rows share every LDS op) ----
    bfly8<false>(ar, ai); tw_apply<false>(ar, ai, c1, s1);
    bfly8<false>(br, bi); tw_apply<false>(br, bi, c1, s1);
#pragma unroll
    for (int k = 0; k < 8; ++k) buf[st1 + k] = make_float4(ar[k], ai[k], br[k], bi[k]);
#pragma unroll
    for (int k = 0; k < 8; ++k) {
        float4 v = buf[ld0 + 72 * k];
        ar[k] = v.x; ai[k] = v.y; br[k] = v.z; bi[k] = v.w;
    }
    bfly8<false>(ar, ai); tw_apply<false>(ar, ai, c8, s8);
    bfly8<false>(br, bi); tw_apply<false>(br, bi, c8, s8);
#pragma unroll
    for (int k = 0; k < 8; ++k) buf[st2 + 9 * k] = make_float4(ar[k], ai[k], br[k], bi[k]);
#pragma unroll
    for (int k = 0; k < 8; ++k) {
        float4 v = buf[ld0 + 72 * k];
        ar[k] = v.x; ai[k] = v.y; br[k] = v.z; bi[k] = v.w;
    }
    bfly8<false>(ar, ai);
    bfly8<false>(br, bi);
    // regs now hold Z[t + 64k] in natural order (both rows).

    // ---- mirror via LDS: write Z at pad(e), read pad((512-e)&511) ----
#pragma unroll
    for (int k = 0; k < 8; ++k) buf[ld0 + 72 * k] = make_float4(ar[k], ai[k], br[k], bi[k]);
#pragma unroll
    for (int k = 0; k < 8; ++k) {
        int m = (512 - (t + 64 * k)) & 511;
        float4 v = buf[m + (m >> 3)];        // (ArM, AiM, BrM, BiM)
        // W = P*Z + i*q*conj(Zm):  nr = P*zr + q*Im(Zm), ni = P*zi + q*Re(Zm)
        float nrA = pqx[k] * ar[k] + pqy[k] * v.y;
        float niA = pqx[k] * ai[k] + pqy[k] * v.x;
        float nrB = pqx[k] * br[k] + pqy[k] * v.w;
        float niB = pqx[k] * bi[k] + pqy[k] * v.z;
        ar[k] = nrA; ai[k] = niA; br[k] = nrB; bi[k] = niB;
    }

    // ---- inverse FFT-512 (input already in stage-1 read layout) ----
    bfly8<true>(ar, ai); tw_apply<true>(ar, ai, c1, s1);
    bfly8<true>(br, bi); tw_apply<true>(br, bi, c1, s1);
#pragma unroll
    for (int k = 0; k < 8; ++k) buf[st1 + k] = make_float4(ar[k], ai[k], br[k], bi[k]);
#pragma unroll
    for (int k = 0; k < 8; ++k) {
        float4 v = buf[ld0 + 72 * k];
        ar[k] = v.x; ai[k] = v.y; br[k] = v.z; bi[k] = v.w;
    }
    bfly8<true>(ar, ai); tw_apply<true>(ar, ai, c8, s8);
    bfly8<true>(br, bi); tw_apply<true>(br, bi, c8, s8);
#pragma unroll
    for (int k = 0; k < 8; ++k) buf[st2 + 9 * k] = make_float4(ar[k], ai[k], br[k], bi[k]);
#pragma unroll
    for (int k = 0; k < 8; ++k) {
        float4 v = buf[ld0 + 72 * k];
        ar[k] = v.x; ai[k] = v.y; br[k] = v.z; bi[k] = v.w;
    }
    bfly8<true>(ar, ai);
    bfly8<true>(br, bi);

    // ---- exit bounce: write natural paired, read bin-pairs, dwordx4 stores ----
#pragma unroll
    for (int k = 0; k < 8; ++k)
        buf[ld0 + 72 * k] = make_float4(ar[k], ai[k], br[k], bi[k]);
#pragma unroll
    for (int j = 0; j < 4; ++j) {
        int b0 = 2 * t + 128 * j;
        int a0 = b0 + (b0 >> 3);
        float4 e = buf[a0];                  // bin b0:   (Ar,Ai,Br,Bi)
        float4 o = buf[a0 + 1];              // bin b0+1: (Ar,Ai,Br,Bi)
        out4[baseA4 + t + 64 * j] = make_float4(e.x, e.y, o.x, o.y);
        out4[baseB4 + t + 64 * j] = make_float4(e.z, e.w, o.z, o.w);
    }
}

// Build softmax gate -> (P,q) table and twiddle tables, all in d_ws.
__global__ void gate_kernel(const float* __restrict__ w1,
                            float2* __restrict__ pq,
                            float2* __restrict__ tw1,
                            float2* __restrict__ tw8)
{
    __shared__ float red[1024];
    __shared__ float ex[513];
    const int t = threadIdx.x;  // 1024 threads

    float v = (t < 513) ? w1[t] : -1e30f;
    red[t] = v;
    __syncthreads();
    for (int off = 512; off > 0; off >>= 1) {
        if (t < off) red[t] = fmaxf(red[t], red[t + off]);
        __syncthreads();
    }
    float M = red[0];
    __syncthreads();

    float e = (t < 513) ? expf(w1[t] - M) : 0.0f;
    if (t < 513) ex[t] = e;
    red[t] = e;
    __syncthreads();
    for (int off = 512; off > 0; off >>= 1) {
        if (t < off) red[t] += red[t + off];
        __syncthreads();
    }
    float inv = 1.0f / red[0];
    __syncthreads();

    if (t < 512) {
        float ga = ex[t] * inv;
        float gb = ex[512 - t] * inv;
        float gp = ga + gb, gm = ga - gb;
        float th = (float)t * 6.13592315154256492e-03f;  // pi/512 * t = 2*pi*t/1024
        float sn, cs;
        __sincosf(th, &sn, &cs);
        float P = 0.5f * (gp - gm * sn) * (1.0f / 512.0f);
        float q = 0.5f * (gm * cs) * (1.0f / 512.0f);
        pq[t] = make_float2(P, q);
    }
    if (t < 448) {
        int k = (t >> 6) + 1;
        int j = t & 63;
        float th = (float)(j * k) * 1.22718463151036952e-02f;  // 2*pi/512
        float sn, cs;
        sincosf(th, &sn, &cs);
        tw1[t] = make_float2(cs, sn);
    }
    if (t < 56) {
        int k = (t >> 3) + 1;
        int p = t & 7;
        float th = (float)(p * k) * 9.81747704246810387e-02f;  // 2*pi/64
        float sn, cs;
        sincosf(th, &sn, &cs);
        tw8[t] = make_float2(cs, sn);
    }
}

extern "C" void kernel_launch(void* const* d_in, const int* in_sizes, int n_in,
                              void* d_out, int out_size, void* d_ws, size_t ws_size,
                              hipStream_t stream)
{
    (void)n_in; (void)out_size; (void)ws_size;
    const float4* hidden = (const float4*)d_in[0];   // [32768 rows, 256 float4]
    const float*  w1     = (const float*)d_in[1];    // [513]
    float4* out = (float4*)d_out;

    float2* pq  = (float2*)d_ws;          // 512 float2
    float2* tw1 = pq + 512;               // 448 float2
    float2* tw8 = tw1 + 448;              // 56  float2

    gate_kernel<<<1, 1024, 0, stream>>>(w1, pq, tw1, tw8);

    const int rows   = in_sizes[0] / 1024;   // 32768
    const int blocks = rows / 8;             // 4096 (8 rows per block, 2/wave)
    fv_kernel<<<blocks, 256, 0, stream>>>(hidden, pq, tw1, tw8, out);
}